// Round 3
// baseline (229.000 us; speedup 1.0000x reference)
//
#include <hip/hip_runtime.h>
#include <cstdint>
#include <cstddef>

#define TT 512
#define BB 128
#define EE 128
#define SS 1024
#define NEG_INF (-1e30f)

typedef _Float16 half8 __attribute__((ext_vector_type(8)));
typedef float floatx4 __attribute__((ext_vector_type(4)));

// ---------- fp16 helpers ----------
__device__ __forceinline__ unsigned int pkh(float x, float y) {
    _Float16 hx = (_Float16)x, hy = (_Float16)y;
    unsigned short bx, by;
    __builtin_memcpy(&bx, &hx, 2); __builtin_memcpy(&by, &hy, 2);
    return (unsigned int)bx | ((unsigned int)by << 16);
}

__device__ __forceinline__ float rdlane(float x, int l) {
    return __int_as_float(__builtin_amdgcn_readlane(__float_as_int(x), l));
}

// ============================================================
// prefixF: per-b prefix sums + range-max precompute.
// Now emits CS in B-MAJOR (CSb[b][t]) for calcM4; BvT t-major
// dropped (no consumer).
// ============================================================
__global__ __launch_bounds__(64) void prefixF(
    const float* __restrict__ d1, const float* __restrict__ d2,
    const float* __restrict__ u,
    float* __restrict__ F, float* __restrict__ Bv,
    float* __restrict__ d2T, float* __restrict__ FT,
    float* __restrict__ CSb, float* __restrict__ CMT,
    float* __restrict__ HT)
{
    const int b = blockIdx.x;
    const int lane = threadIdx.x;
    const int t0 = lane * 8;

    float l1[8], l2[8], g[8];
#pragma unroll
    for (int j = 0; j < 8; ++j) {
        const int t = t0 + j;
        l1[j] = d1[t * BB + b];
        l2[j] = d2[t * BB + b];
        g[j] = u[t * BB + b] - l1[j] - l2[j];
    }
    float p[8], s = 0.f;
#pragma unroll
    for (int j = 0; j < 8; ++j) { s += g[j]; p[j] = s; }

    float v = s;
#pragma unroll
    for (int off = 1; off < 64; off <<= 1) {
        float o = __shfl_up(v, off);
        if (lane >= off) v += o;
    }
    const float excl = v - s;

    float Fv[8];
#pragma unroll
    for (int j = 0; j < 8; ++j) Fv[j] = excl + p[j];

#pragma unroll
    for (int j = 0; j < 8; ++j) {
        const int t = t0 + j;
        const float Fm1 = (j > 0) ? Fv[j - 1] : excl;
        const float Bvv = Fm1 - l1[j];
        F  [b * TT + t] = Fv[j];
        Bv [b * TT + t] = Bvv;
        d2T[b * TT + t] = l2[j];
        FT [t * BB + b] = Fv[j];
    }

    // ---- range-max structures (chunk = 32 t = 4 lanes) ----
    float pm[8], sm[8];
    pm[0] = Fv[0];
#pragma unroll
    for (int j = 1; j < 8; ++j) pm[j] = fmaxf(pm[j - 1], Fv[j]);
    sm[7] = Fv[7];
#pragma unroll
    for (int j = 6; j >= 0; --j) sm[j] = fmaxf(sm[j + 1], Fv[j]);

    float pcar = NEG_INF, scar = NEG_INF;
#pragma unroll
    for (int off = 1; off <= 3; ++off) {
        float xu = __shfl_up(pm[7], off);
        if ((lane & 3) >= off) pcar = fmaxf(pcar, xu);
        float xd = __shfl_down(sm[0], off);
        if ((lane & 3) + off <= 3) scar = fmaxf(scar, xd);
    }

#pragma unroll
    for (int j = 0; j < 8; ++j) {
        const int t = t0 + j;
        const float Hv  = fmaxf(pcar, (j > 0) ? pm[j - 1] : NEG_INF);
        const float CSv = fmaxf(sm[j], scar);
        HT [t * BB + b] = Hv;
        CSb[b * TT + t] = CSv;          // b-major for calcM4
    }
    if ((lane & 3) == 0)
        CMT[(lane >> 2) * BB + b] = fmaxf(sm[0], scar);
}

// ============================================================
// calcM4: lane <-> output column (i), register-accumulated
// reduction over b.  Zero LDS, zero barriers.
//   block per t (big-t first), 4 waves; wave w handles 64-i
//   groups g = w, w+4, ...  Per b-iteration: 2 coalesced loads
//   (CSb/Bvb row slices) + readlane broadcasts of Ft[b]/K[b].
//   Diagonal group additionally does a 6-step in-wave suffix-max
//   scan of F[b][i] (exact fmax composition -> bit-identical).
// ============================================================
__global__ __launch_bounds__(256) void calcM4(
    const float* __restrict__ Fb,   // [b][t]
    const float* __restrict__ Bvb,  // [b][t]
    const float* __restrict__ CSb,  // [b][t]
    const float* __restrict__ FT,   // [t][b]
    const float* __restrict__ CMT,  // [16][b]
    const float* __restrict__ HT,   // [t][b]
    const float* __restrict__ u,    // [t][b]
    float* __restrict__ m)
{
    const int t = (TT - 1) - (int)blockIdx.x;   // big t first
    const int tid = threadIdx.x;
    const int w = tid >> 6, lane = tid & 63;
    const int ct = t >> 5;
    const int ngroups = (t >> 6) + 1;

    // per-lane holders of per-b scalars (b = lane and b = lane+64)
    const float Ft_a = FT[t * BB + lane],      Ft_b = FT[t * BB + 64 + lane];
    const float u_a  = u [t * BB + lane],      u_b  = u [t * BB + 64 + lane];
    const float H_a  = HT[t * BB + lane],      H_b  = HT[t * BB + 64 + lane];

    for (int g = w; g < ngroups; g += 4) {
        const int i = (g << 6) + lane;
        const bool diagGrp = (g == ngroups - 1);
        const bool upper = (lane >= 32);

        // K0: chunk 2g   -> max(H, CM[2g+1 .. ct-1])
        // K1: chunk 2g+1 -> max(H, CM[2g+2 .. ct-1])
        float K0a = H_a, K0b = H_b, K1a = H_a, K1b = H_b;
        for (int c = 2 * g + 1; c < ct; ++c) {
            const float ma = CMT[c * BB + lane];
            const float mb = CMT[c * BB + 64 + lane];
            K0a = fmaxf(K0a, ma); K0b = fmaxf(K0b, mb);
            if (c > 2 * g + 1) { K1a = fmaxf(K1a, ma); K1b = fmaxf(K1b, mb); }
        }

        float acc0 = NEG_INF, acc1 = NEG_INF;
        const float* csp = CSb + i;
        const float* bvp = Bvb + i;
        const float* fbp = Fb  + i;

        if (!diagGrp) {
            // all lanes strictly off-diagonal (i < t guaranteed)
#pragma unroll 4
            for (int b = 0; b < 64; ++b) {
                const float cs = csp[b * TT];
                const float bv = bvp[b * TT];
                const float Kc  = upper ? rdlane(K1a, b) : rdlane(K0a, b);
                const float Fts = rdlane(Ft_a, b);
                const float R = fmaxf(cs, Kc);
                acc0 = fmaxf(acc0, Fts - fmaxf(bv, R));
                acc1 = fmaxf(acc1, Fts - R);
            }
#pragma unroll 4
            for (int b = 0; b < 64; ++b) {
                const float cs = csp[(b + 64) * TT];
                const float bv = bvp[(b + 64) * TT];
                const float Kc  = upper ? rdlane(K1b, b) : rdlane(K0b, b);
                const float Fts = rdlane(Ft_b, b);
                const float R = fmaxf(cs, Kc);
                acc0 = fmaxf(acc0, Fts - fmaxf(bv, R));
                acc1 = fmaxf(acc1, Fts - R);
            }
        } else {
            const bool isDiag = ((i >> 5) == ct);
#pragma unroll 2
            for (int bo = 0; bo < 128; ++bo) {
                const bool lo = (bo < 64);
                const int bl = lo ? bo : bo - 64;
                const float cs = csp[bo * TT];
                const float bv = bvp[bo * TT];
                const float fl = fbp[bo * TT];
                const float Kc  = upper ? (lo ? rdlane(K1a, bl) : rdlane(K1b, bl))
                                        : (lo ? rdlane(K0a, bl) : rdlane(K0b, bl));
                const float Fts = lo ? rdlane(Ft_a, bl) : rdlane(Ft_b, bl);
                const float us  = lo ? rdlane(u_a, bl)  : rdlane(u_b, bl);
                // in-wave suffix-max of masked F (i ascending with lane)
                float x = (i < t) ? fl : NEG_INF;
#pragma unroll
                for (int off = 1; off < 64; off <<= 1) {
                    const float y = __shfl_down(x, off);
                    if (lane + off < 64) x = fmaxf(x, y);
                }
                const float R = isDiag ? x : fmaxf(cs, Kc);
                acc0 = fmaxf(acc0, Fts - fmaxf(bv, R));
                acc1 = fmaxf(acc1, (i == t) ? us : (Fts - R));
            }
        }

        if (i <= t)
            *(float2*)&m[(size_t)t * SS + 2 * i] = make_float2(acc0, acc1);
    }
}

// ============================================================
// phaseC_mfma: out[t,b,:] = sum_s min(a(i,t), m[t,s]) * V[b,s,:]
// (reverted to the round-1 1-deep pipeline version, 96 VGPR)
// ============================================================
#define WSO 0
#define VTO 2304
#define FRO 6912
#define S0O 7488
#define BVO 8064
#define LTO 8640
#define D2O 9088

__device__ __forceinline__ float tileQ(const float* Lt, int lo, int hi) {
    const int len = hi - lo + 1;                  // >= 1
    const int j = 31 - __builtin_clz(len);
    return fmaxf(Lt[j * 64 + lo], Lt[j * 64 + hi + 1 - (1 << j)]);
}

__global__ __launch_bounds__(256) void phaseC_mfma(
    const float* __restrict__ F, const float* __restrict__ Bvg,
    const float* __restrict__ d2T, const float* __restrict__ m,
    const float* __restrict__ v1, const float* __restrict__ v2,
    float* __restrict__ out)
{
    const int b  = blockIdx.x & (BB - 1);
    const int k8 = blockIdx.x >> 7;
    // balanced remap: quartets {k8, k8+2, k8+4, k8+6} sum to 36 chunks.
    const int tt = 7 - (k8 ^ (((k8 + 2) >> 2) & 1));
    const int t0 = tt * 64;
    const int tid = threadIdx.x;

    __shared__ float sh[9152];

    // per-thread roles
    const int lane = tid & 63, w = tid >> 6;
    const int wr = w >> 1, wc = w & 1;            // 2x2 wave grid
    const int n = lane & 15;
    const int kq = (lane >> 4) * 8;
    const int il = tid & 31, g = tid >> 5;        // W staging
    const int veb = tid & 7;                      // V staging: e quad
    const int vip = ((tid >> 3) & 7) + 8 * wc;    // i-pair 0..15
    const int veh = wr * 64;                      // e half
    const float* Lt = &sh[LTO];
    const int nchunks = 2 * tt + 2;

    // ---------- pipeline registers ----------
    float4 pv[8];
    float2 pmv[8];

    auto prefetch = [&](int ck) {
        const int ib = 32 * ck;
        const int i = ib + il;
#pragma unroll
        for (int r8 = 0; r8 < 8; ++r8) {
            const int t = t0 + 8 * g + r8;
            pmv[r8] = *(const float2*)&m[(size_t)t * SS + 2 * i];
        }
        const int i0 = ib + 2 * vip, i1 = i0 + 1;
        const float* p10 = v1 + ((size_t)i0 * BB + b) * EE;
        const float* p11 = v1 + ((size_t)i1 * BB + b) * EE;
        const float* p20 = v2 + ((size_t)i0 * BB + b) * EE;
        const float* p21 = v2 + ((size_t)i1 * BB + b) * EE;
#pragma unroll
        for (int c = 0; c < 2; ++c) {
            const int e0 = 4 * veb + 32 * c + veh;
            pv[4 * c + 0] = *(const float4*)&p10[e0];
            pv[4 * c + 1] = *(const float4*)&p11[e0];
            pv[4 * c + 2] = *(const float4*)&p20[e0];
            pv[4 * c + 3] = *(const float4*)&p21[e0];
        }
    };

    const int nF = t0 + 64;
    for (int k = tid; k < nF; k += 256) {
        sh[FRO + k] = F[b * TT + k];
        sh[BVO + k] = Bvg[b * TT + k];
    }
    if (tid < 64) sh[D2O + tid] = d2T[b * TT + t0 + tid];

    // issue chunk-0 global loads early: latency hides under the
    // S0/Lt prologue scan below.
    prefetch(0);

    __syncthreads();

    // S0[k] = max F over [k, t0-1]   (NEG_INF for k >= t0)
    {
        const int k1 = tid, k2 = tid + 256, k3 = tid + 512;
        sh[S0O + k1] = (k1 < t0) ? sh[FRO + k1] : NEG_INF;
        sh[S0O + k2] = (k2 < t0) ? sh[FRO + k2] : NEG_INF;
        if (k3 < 576) sh[S0O + k3] = NEG_INF;
        if (tid < 64) sh[LTO + tid] = sh[FRO + t0 + tid];   // Lt[0]
        __syncthreads();
        for (int off = 1; off < t0; off <<= 1) {
            float a1 = sh[S0O + k1]; if (k1 + off < 576) a1 = fmaxf(a1, sh[S0O + k1 + off]);
            float a2 = sh[S0O + k2]; if (k2 + off < 576) a2 = fmaxf(a2, sh[S0O + k2 + off]);
            __syncthreads();
            sh[S0O + k1] = a1; sh[S0O + k2] = a2;
            __syncthreads();
        }
        for (int j = 1; j < 7; ++j) {
            float v = 0.f;
            if (tid < 64)
                v = fmaxf(sh[LTO + (j - 1) * 64 + tid],
                          sh[LTO + (j - 1) * 64 + min(tid + (1 << (j - 1)), 63)]);
            __syncthreads();
            if (tid < 64) sh[LTO + j * 64 + tid] = v;
            __syncthreads();
        }
    }

    floatx4 acc[2][4];
#pragma unroll
    for (int r = 0; r < 2; ++r)
#pragma unroll
        for (int j = 0; j < 4; ++j) acc[r][j] = (floatx4)0.f;

    for (int ck = 0; ck < nchunks; ++ck) {
        const int ib = 32 * ck;

        // ---- W closed form + min(m) -> registers (static LDS only) ----
        unsigned int wreg[8];
        {
            const int i = ib + il;
            const float Ai = (i > 0) ? sh[FRO + i - 1] : 0.f;
            const float Bi = sh[BVO + i];
            const bool below = (i < t0);
            const float S0i = below ? sh[S0O + i] : 0.f;
#pragma unroll
            for (int r8 = 0; r8 < 8; ++r8) {
                const int t_l = 8 * g + r8;
                const int t = t0 + t_l;
                float w0 = 0.f, w1 = 0.f;
                if (i <= t) {
                    float R;
                    if (below) {
                        const float qq = (t_l > 0) ? tileQ(Lt, 0, t_l - 1) : NEG_INF;
                        R = fmaxf(S0i, qq);
                    } else {
                        const int li = i - t0;
                        R = (t_l - 1 >= li) ? tileQ(Lt, li, t_l - 1) : NEG_INF;
                    }
                    const float2 mv = pmv[r8];
                    const float a0 = fmaxf(Ai, R) - fmaxf(Bi, R);
                    const float a1 = (i == t) ? sh[D2O + t_l] : fmaxf(Bi - R, 0.f);
                    w0 = fminf(a0, mv.x);
                    w1 = fminf(a1, mv.y);
                }
                wreg[r8] = pkh(w0, w1);
            }
        }

        // ---- pack V fp16 -> registers ----
        uint2 vreg[8];
#pragma unroll
        for (int c = 0; c < 2; ++c) {
            const float4 xa = pv[4 * c + 0], xb = pv[4 * c + 1];
            const float4 ya = pv[4 * c + 2], yb = pv[4 * c + 3];
            vreg[4 * c + 0] = make_uint2(pkh(xa.x, ya.x), pkh(xb.x, yb.x));
            vreg[4 * c + 1] = make_uint2(pkh(xa.y, ya.y), pkh(xb.y, yb.y));
            vreg[4 * c + 2] = make_uint2(pkh(xa.z, ya.z), pkh(xb.z, yb.z));
            vreg[4 * c + 3] = make_uint2(pkh(xa.w, ya.w), pkh(xb.w, yb.w));
        }

        __syncthreads();                 // MFMA(ck-1) done reading LDS

        // ---- raw LDS writes only between the barriers ----
#pragma unroll
        for (int r8 = 0; r8 < 8; ++r8)
            ((unsigned int*)sh)[(8 * g + r8) * 36 + il] = wreg[r8];
        {
            unsigned int* vt = (unsigned int*)sh + VTO;
            const int dw = 2 * vip;
#pragma unroll
            for (int c = 0; c < 2; ++c) {
                const int e0 = 4 * veb + 32 * c + veh;
                *(uint2*)&vt[(e0 + 0) * 36 + dw] = vreg[4 * c + 0];
                *(uint2*)&vt[(e0 + 1) * 36 + dw] = vreg[4 * c + 1];
                *(uint2*)&vt[(e0 + 2) * 36 + dw] = vreg[4 * c + 2];
                *(uint2*)&vt[(e0 + 3) * 36 + dw] = vreg[4 * c + 3];
            }
        }

        __syncthreads();                 // staging visible

        // ---- issue NEXT chunk's global loads; latency hides under MFMA
        if (ck + 1 < nchunks) prefetch(ck + 1);

        // ---- MFMA: 2 k-steps x (2 t-rows x 4 e-tiles) per wave ----
        __builtin_amdgcn_s_setprio(1);
        {
            const _Float16* WsH = (const _Float16*)sh;
            const _Float16* VtH = (const _Float16*)(sh + VTO);
#pragma unroll
            for (int k2 = 0; k2 < 64; k2 += 32) {
                const half8 av0 = *(const half8*)&WsH[(32 * wr + n) * 72 + kq + k2];
                const half8 av1 = *(const half8*)&WsH[(32 * wr + 16 + n) * 72 + kq + k2];
#pragma unroll
                for (int j = 0; j < 4; ++j) {
                    const half8 bv = *(const half8*)&VtH[(64 * wc + 16 * j + n) * 72 + kq + k2];
                    acc[0][j] = __builtin_amdgcn_mfma_f32_16x16x32_f16(av0, bv, acc[0][j], 0, 0, 0);
                    acc[1][j] = __builtin_amdgcn_mfma_f32_16x16x32_f16(av1, bv, acc[1][j], 0, 0, 0);
                }
            }
        }
        __builtin_amdgcn_s_setprio(0);
    }

    // ---- epilogue ----
    {
        const int q = lane >> 4;
#pragma unroll
        for (int r = 0; r < 2; ++r) {
#pragma unroll
            for (int j = 0; j < 4; ++j) {
#pragma unroll
                for (int reg = 0; reg < 4; ++reg) {
                    const int t = t0 + 32 * wr + 16 * r + 4 * q + reg;
                    const int col = 64 * wc + 16 * j + n;
                    out[((size_t)t * BB + b) * EE + col] = acc[r][j][reg];
                }
            }
        }
    }
}

// ============================================================
extern "C" void kernel_launch(void* const* d_in, const int* in_sizes, int n_in,
                              void* d_out, int out_size, void* d_ws, size_t ws_size,
                              hipStream_t stream) {
    const float* v1 = (const float*)d_in[0];
    const float* v2 = (const float*)d_in[1];
    const float* d1 = (const float*)d_in[2];
    const float* d2 = (const float*)d_in[3];
    const float* u  = (const float*)d_in[4];
    float* out = (float*)d_out;

    char* ws = (char*)d_ws;
    float* m   = (float*)ws;                                   // 2 MB
    float* F   = m   + (size_t)TT * SS;
    float* Bvp = F   + (size_t)BB * TT;
    float* d2T = Bvp + (size_t)BB * TT;
    float* FT  = d2T + (size_t)BB * TT;
    float* CSb = FT  + (size_t)BB * TT;                        // b-major CS
    float* HT  = CSb + (size_t)BB * TT;
    float* CMT = HT  + (size_t)BB * TT;                        // 16*128

    prefixF<<<dim3(BB), dim3(64), 0, stream>>>(d1, d2, u, F, Bvp, d2T, FT,
                                               CSb, CMT, HT);
    calcM4 <<<dim3(TT), dim3(256), 0, stream>>>(F, Bvp, CSb, FT, CMT, HT, u, m);
    phaseC_mfma<<<dim3(BB * 8), dim3(256), 0, stream>>>(F, Bvp, d2T, m, v1, v2, out);
}

// Round 5
// 226.579 us; speedup vs baseline: 1.0107x; 1.0107x over previous
//
#include <hip/hip_runtime.h>
#include <cstdint>
#include <cstddef>

#define TT 512
#define BB 128
#define EE 128
#define SS 1024
#define NEG_INF (-1e30f)

typedef _Float16 half8 __attribute__((ext_vector_type(8)));
typedef float floatx4 __attribute__((ext_vector_type(4)));

// ---------- fp16 helpers ----------
__device__ __forceinline__ unsigned int pkh(float x, float y) {
    _Float16 hx = (_Float16)x, hy = (_Float16)y;
    unsigned short bx, by;
    __builtin_memcpy(&bx, &hx, 2); __builtin_memcpy(&by, &hy, 2);
    return (unsigned int)bx | ((unsigned int)by << 16);
}

__device__ __forceinline__ unsigned int pkrtz(float x, float y) {
    auto h = __builtin_amdgcn_cvt_pkrtz(x, y);   // __fp16 ext_vector(2)
    unsigned int r; __builtin_memcpy(&r, &h, 4); return r;
}

// ============================================================
// prefixF: per-b prefix sums + range-max precompute. (original)
// ============================================================
__global__ __launch_bounds__(64) void prefixF(
    const float* __restrict__ d1, const float* __restrict__ d2,
    const float* __restrict__ u,
    float* __restrict__ F, float* __restrict__ Bv,
    float* __restrict__ d2T, float* __restrict__ FT,
    float* __restrict__ BvT, float* __restrict__ CST,
    float* __restrict__ CMT, float* __restrict__ HT)
{
    const int b = blockIdx.x;
    const int lane = threadIdx.x;
    const int t0 = lane * 8;

    float l1[8], l2[8], g[8];
#pragma unroll
    for (int j = 0; j < 8; ++j) {
        const int t = t0 + j;
        l1[j] = d1[t * BB + b];
        l2[j] = d2[t * BB + b];
        g[j] = u[t * BB + b] - l1[j] - l2[j];
    }
    float p[8], s = 0.f;
#pragma unroll
    for (int j = 0; j < 8; ++j) { s += g[j]; p[j] = s; }

    float v = s;
#pragma unroll
    for (int off = 1; off < 64; off <<= 1) {
        float o = __shfl_up(v, off);
        if (lane >= off) v += o;
    }
    const float excl = v - s;

    float Fv[8];
#pragma unroll
    for (int j = 0; j < 8; ++j) Fv[j] = excl + p[j];

#pragma unroll
    for (int j = 0; j < 8; ++j) {
        const int t = t0 + j;
        const float Fm1 = (j > 0) ? Fv[j - 1] : excl;
        const float Bvv = Fm1 - l1[j];
        F  [b * TT + t] = Fv[j];
        Bv [b * TT + t] = Bvv;
        d2T[b * TT + t] = l2[j];
        FT [t * BB + b] = Fv[j];
        BvT[t * BB + b] = Bvv;
    }

    // ---- range-max structures (chunk = 32 t = 4 lanes) ----
    float pm[8], sm[8];
    pm[0] = Fv[0];
#pragma unroll
    for (int j = 1; j < 8; ++j) pm[j] = fmaxf(pm[j - 1], Fv[j]);
    sm[7] = Fv[7];
#pragma unroll
    for (int j = 6; j >= 0; --j) sm[j] = fmaxf(sm[j + 1], Fv[j]);

    float pcar = NEG_INF, scar = NEG_INF;
#pragma unroll
    for (int off = 1; off <= 3; ++off) {
        float xu = __shfl_up(pm[7], off);
        if ((lane & 3) >= off) pcar = fmaxf(pcar, xu);
        float xd = __shfl_down(sm[0], off);
        if ((lane & 3) + off <= 3) scar = fmaxf(scar, xd);
    }

#pragma unroll
    for (int j = 0; j < 8; ++j) {
        const int t = t0 + j;
        const float Hv  = fmaxf(pcar, (j > 0) ? pm[j - 1] : NEG_INF);
        const float CSv = fmaxf(sm[j], scar);
        HT [t * BB + b] = Hv;
        CST[t * BB + b] = CSv;
    }
    if ((lane & 3) == 0)
        CMT[(lane >> 2) * BB + b] = fmaxf(sm[0], scar);
}

// ============================================================
// calcM2 (restored original — measured ~11 us)
// ============================================================
__global__ __launch_bounds__(256) void calcM2(
    const float* __restrict__ FT, const float* __restrict__ BvT,
    const float* __restrict__ CST, const float* __restrict__ CMT,
    const float* __restrict__ HT, const float* __restrict__ u,
    float* __restrict__ m)
{
    const int t = (int)blockIdx.y;
    const int ci = (int)blockIdx.x;
    const int ct = t >> 5;
    if (ci > ct) return;

    const int tid = threadIdx.x;
    const int b = tid & 127, h = tid >> 7;
    const int ib = 32 * ci;

    __shared__ float cand[BB][66];
    __shared__ float Tot[2][BB];
    __shared__ float red[4][64];

    const float Ft = FT[t * BB + b];

    if (ci < ct) {
        float K = HT[t * BB + b];
        for (int c = ci + 1; c < ct; ++c) K = fmaxf(K, CMT[c * BB + b]);
#pragma unroll
        for (int j = 0; j < 16; ++j) {
            const int jj = 16 * h + j;
            const int i = ib + jj;
            const float R = fmaxf(CST[i * BB + b], K);
            const float Bvv = BvT[i * BB + b];
            cand[b][2 * jj]     = Ft - fmaxf(Bvv, R);
            cand[b][2 * jj + 1] = Ft - R;
        }
    } else {
        float vv[16], sfx[16];
#pragma unroll
        for (int j = 0; j < 16; ++j) {
            const int i = ib + 16 * h + j;
            vv[j] = (i < t) ? FT[i * BB + b] : NEG_INF;
        }
        sfx[15] = vv[15];
#pragma unroll
        for (int j = 14; j >= 0; --j) sfx[j] = fmaxf(vv[j], sfx[j + 1]);
        Tot[h][b] = sfx[0];
        __syncthreads();
        const float carry = (h == 0) ? Tot[1][b] : NEG_INF;
        const float ub = u[t * BB + b];
#pragma unroll
        for (int j = 0; j < 16; ++j) {
            const int jj = 16 * h + j;
            const int i = ib + jj;
            const float R = fmaxf(sfx[j], carry);
            const float Bvv = BvT[i * BB + b];
            cand[b][2 * jj]     = Ft - fmaxf(Bvv, R);
            cand[b][2 * jj + 1] = (i == t) ? ub : (Ft - R);
        }
    }
    __syncthreads();

    {
        const int s = tid & 63, g = tid >> 6;
        float mx = NEG_INF;
        const int b0 = g * 32;
#pragma unroll 8
        for (int bb = b0; bb < b0 + 32; ++bb) mx = fmaxf(mx, cand[bb][s]);
        red[g][s] = mx;
    }
    __syncthreads();
    if (tid < 64) {
        const float r = fmaxf(fmaxf(red[0][tid], red[1][tid]),
                              fmaxf(red[2][tid], red[3][tid]));
        const int s_glob = 64 * ci + tid;
        if (s_glob < 2 * t + 2) m[(size_t)t * SS + s_glob] = r;
    }
}

// ============================================================
// phaseC_mfma: out[t,b,:] = sum_s min(a(i,t), m[t,s]) * V[b,s,:]
// Round-4/5 changes vs R1:
//  - incremental running range-max (Freg2[8] + TP[8g]) replaces
//    tileQ (2 LDS reads + clz per r8) and the whole Lt ladder.
//    Exact fmax composition -> bit-identical.
//  - LDS row pitch 72 -> 68 halfwords: MFMA ds_read_b128 start
//    bank 4(n+q) -> 2n+4q: 8-way -> ~4-way conflict.
//  - V-pack via v_cvt_pkrtz (1 instr/pair).
//  - LDS 36.9 -> 33.0 KB.
// ============================================================
#define PWH 68                 // row pitch in halfwords
#define PWW 34                 // row pitch in words
#define VTO 2176               // Ws = 64*34 words
#define FRO 6528               // Vt = 128*34 words
#define S0O 7040
#define BVO 7616
#define D2O 8128
#define TPO 8192
// total 8256 floats = 33024 B

__global__ __launch_bounds__(256) void phaseC_mfma(
    const float* __restrict__ F, const float* __restrict__ Bvg,
    const float* __restrict__ d2T, const float* __restrict__ m,
    const float* __restrict__ v1, const float* __restrict__ v2,
    float* __restrict__ out)
{
    const int b  = blockIdx.x & (BB - 1);
    const int k8 = blockIdx.x >> 7;
    // balanced remap: quartets {k8, k8+2, k8+4, k8+6} sum to 36 chunks.
    const int tt = 7 - (k8 ^ (((k8 + 2) >> 2) & 1));
    const int t0 = tt * 64;
    const int tid = threadIdx.x;

    __shared__ float sh[8256];

    const int lane = tid & 63, w = tid >> 6;
    const int wr = w >> 1, wc = w & 1;            // 2x2 wave grid
    const int n = lane & 15;
    const int kq = (lane >> 4) * 8;
    const int il = tid & 31, g = tid >> 5;        // W staging
    const int veb = tid & 7;                      // V staging: e quad
    const int vip = ((tid >> 3) & 7) + 8 * wc;    // i-pair 0..15
    const int veh = wr * 64;                      // e half
    const int nchunks = 2 * tt + 2;

    // ---------- pipeline registers ----------
    float4 pv[8];
    float2 pmv[8];

    auto prefetch = [&](int ck) {
        const int ib = 32 * ck;
        const int i = ib + il;
#pragma unroll
        for (int r8 = 0; r8 < 8; ++r8) {
            const int t = t0 + 8 * g + r8;
            pmv[r8] = *(const float2*)&m[(size_t)t * SS + 2 * i];
        }
        const int i0 = ib + 2 * vip, i1 = i0 + 1;
        const float* p10 = v1 + ((size_t)i0 * BB + b) * EE;
        const float* p11 = v1 + ((size_t)i1 * BB + b) * EE;
        const float* p20 = v2 + ((size_t)i0 * BB + b) * EE;
        const float* p21 = v2 + ((size_t)i1 * BB + b) * EE;
#pragma unroll
        for (int c = 0; c < 2; ++c) {
            const int e0 = 4 * veb + 32 * c + veh;
            pv[4 * c + 0] = *(const float4*)&p10[e0];
            pv[4 * c + 1] = *(const float4*)&p11[e0];
            pv[4 * c + 2] = *(const float4*)&p20[e0];
            pv[4 * c + 3] = *(const float4*)&p21[e0];
        }
    };

    const int nF = t0 + 64;
    for (int k = tid; k < nF; k += 256) {
        sh[FRO + k] = F[b * TT + k];
        sh[BVO + k] = Bvg[b * TT + k];
    }
    if (tid < 64) sh[D2O + tid] = d2T[b * TT + t0 + tid];

    // issue chunk-0 global loads early: latency hides under prologue
    prefetch(0);

    __syncthreads();

    // S0[k] = max F over [k, t0-1]; TP[j] = max F over [t0, t0+j-1]
    {
        const int k1 = tid, k2 = tid + 256, k3 = tid + 512;
        sh[S0O + k1] = (k1 < t0) ? sh[FRO + k1] : NEG_INF;
        sh[S0O + k2] = (k2 < t0) ? sh[FRO + k2] : NEG_INF;
        if (k3 < 576) sh[S0O + k3] = NEG_INF;
        if (tid < 64) {
            float xi = sh[FRO + t0 + tid];
#pragma unroll
            for (int off = 1; off < 64; off <<= 1) {
                const float y = __shfl_up(xi, off);
                if (tid >= off) xi = fmaxf(xi, y);
            }
            const float ex = __shfl_up(xi, 1);
            sh[TPO + tid] = (tid == 0) ? NEG_INF : ex;
        }
        __syncthreads();
        for (int off = 1; off < t0; off <<= 1) {
            float a1 = sh[S0O + k1]; if (k1 + off < 576) a1 = fmaxf(a1, sh[S0O + k1 + off]);
            float a2 = sh[S0O + k2]; if (k2 + off < 576) a2 = fmaxf(a2, sh[S0O + k2 + off]);
            __syncthreads();
            sh[S0O + k1] = a1; sh[S0O + k2] = a2;
            __syncthreads();
        }
    }

    // per-thread constants for incremental range-max
    float Freg2[8];
#pragma unroll
    for (int j = 0; j < 8; ++j) Freg2[j] = sh[FRO + t0 + 8 * g + j];
    const float qstart = sh[TPO + 8 * g];

    floatx4 acc[2][4];
#pragma unroll
    for (int r = 0; r < 2; ++r)
#pragma unroll
        for (int j = 0; j < 4; ++j) acc[r][j] = (floatx4)0.f;

    for (int ck = 0; ck < nchunks; ++ck) {
        const int ib = 32 * ck;
        const int i = ib + il;
        const bool below = (ib < t0);          // wave-uniform per chunk

        // ---- W closed form + min(m) -> registers ----
        unsigned int wreg[8];
        {
            const float Ai = (i > 0) ? sh[FRO + i - 1] : 0.f;
            const float Bi = sh[BVO + i];
            const int li = i - t0;
            float q, S0i = 0.f;
            if (below) {
                S0i = sh[S0O + i];
                q = qstart;
            } else {
                q = NEG_INF;
                for (int k = li; k < 8 * g; ++k)
                    q = fmaxf(q, sh[FRO + t0 + k]);
            }
#pragma unroll
            for (int r8 = 0; r8 < 8; ++r8) {
                const int t_l = 8 * g + r8;
                const float2 mv = pmv[r8];
                float w0 = 0.f, w1 = 0.f;
                if (below) {
                    const float R = fmaxf(S0i, q);
                    const float a0 = fmaxf(Ai, R) - fmaxf(Bi, R);
                    const float a1 = fmaxf(Bi - R, 0.f);
                    w0 = fminf(a0, mv.x);
                    w1 = fminf(a1, mv.y);
                    q = fmaxf(q, Freg2[r8]);
                } else {
                    if (li <= t_l) {
                        const float R = q;
                        const float a0 = fmaxf(Ai, R) - fmaxf(Bi, R);
                        const float a1 = (li == t_l) ? sh[D2O + t_l]
                                                     : fmaxf(Bi - R, 0.f);
                        w0 = fminf(a0, mv.x);
                        w1 = fminf(a1, mv.y);
                    }
                    q = fmaxf(q, (t_l >= li) ? Freg2[r8] : NEG_INF);
                }
                wreg[r8] = pkh(w0, w1);
            }
        }

        // ---- pack V fp16 -> registers (cvt_pkrtz) ----
        uint2 vreg[8];
#pragma unroll
        for (int c = 0; c < 2; ++c) {
            const float4 xa = pv[4 * c + 0], xb = pv[4 * c + 1];
            const float4 ya = pv[4 * c + 2], yb = pv[4 * c + 3];
            vreg[4 * c + 0] = make_uint2(pkrtz(xa.x, ya.x), pkrtz(xb.x, yb.x));
            vreg[4 * c + 1] = make_uint2(pkrtz(xa.y, ya.y), pkrtz(xb.y, yb.y));
            vreg[4 * c + 2] = make_uint2(pkrtz(xa.z, ya.z), pkrtz(xb.z, yb.z));
            vreg[4 * c + 3] = make_uint2(pkrtz(xa.w, ya.w), pkrtz(xb.w, yb.w));
        }

        __syncthreads();                 // MFMA(ck-1) done reading LDS

        // ---- raw LDS writes only between the barriers ----
#pragma unroll
        for (int r8 = 0; r8 < 8; ++r8)
            ((unsigned int*)sh)[(8 * g + r8) * PWW + il] = wreg[r8];
        {
            unsigned int* vt = (unsigned int*)sh + VTO;
            const int dw = 2 * vip;
#pragma unroll
            for (int c = 0; c < 2; ++c) {
                const int e0 = 4 * veb + 32 * c + veh;
                *(uint2*)&vt[(e0 + 0) * PWW + dw] = vreg[4 * c + 0];
                *(uint2*)&vt[(e0 + 1) * PWW + dw] = vreg[4 * c + 1];
                *(uint2*)&vt[(e0 + 2) * PWW + dw] = vreg[4 * c + 2];
                *(uint2*)&vt[(e0 + 3) * PWW + dw] = vreg[4 * c + 3];
            }
        }

        __syncthreads();                 // staging visible

        // ---- issue NEXT chunk's global loads; latency hides under MFMA
        if (ck + 1 < nchunks) prefetch(ck + 1);

        // ---- MFMA: 2 k-steps x (2 t-rows x 4 e-tiles) per wave ----
        __builtin_amdgcn_s_setprio(1);
        {
            const _Float16* WsH = (const _Float16*)sh;
            const _Float16* VtH = (const _Float16*)(sh + VTO);
#pragma unroll
            for (int k2 = 0; k2 < 64; k2 += 32) {
                const half8 av0 = *(const half8*)&WsH[(32 * wr + n) * PWH + kq + k2];
                const half8 av1 = *(const half8*)&WsH[(32 * wr + 16 + n) * PWH + kq + k2];
#pragma unroll
                for (int j = 0; j < 4; ++j) {
                    const half8 bv = *(const half8*)&VtH[(64 * wc + 16 * j + n) * PWH + kq + k2];
                    acc[0][j] = __builtin_amdgcn_mfma_f32_16x16x32_f16(av0, bv, acc[0][j], 0, 0, 0);
                    acc[1][j] = __builtin_amdgcn_mfma_f32_16x16x32_f16(av1, bv, acc[1][j], 0, 0, 0);
                }
            }
        }
        __builtin_amdgcn_s_setprio(0);
    }

    // ---- epilogue ----
    {
        const int q = lane >> 4;
#pragma unroll
        for (int r = 0; r < 2; ++r) {
#pragma unroll
            for (int j = 0; j < 4; ++j) {
#pragma unroll
                for (int reg = 0; reg < 4; ++reg) {
                    const int t = t0 + 32 * wr + 16 * r + 4 * q + reg;
                    const int col = 64 * wc + 16 * j + n;
                    out[((size_t)t * BB + b) * EE + col] = acc[r][j][reg];
                }
            }
        }
    }
}

// ============================================================
extern "C" void kernel_launch(void* const* d_in, const int* in_sizes, int n_in,
                              void* d_out, int out_size, void* d_ws, size_t ws_size,
                              hipStream_t stream) {
    const float* v1 = (const float*)d_in[0];
    const float* v2 = (const float*)d_in[1];
    const float* d1 = (const float*)d_in[2];
    const float* d2 = (const float*)d_in[3];
    const float* u  = (const float*)d_in[4];
    float* out = (float*)d_out;

    char* ws = (char*)d_ws;
    float* m   = (float*)ws;                                   // 2 MB
    float* F   = m   + (size_t)TT * SS;
    float* Bvp = F   + (size_t)BB * TT;
    float* d2T = Bvp + (size_t)BB * TT;
    float* FT  = d2T + (size_t)BB * TT;
    float* BvT = FT  + (size_t)BB * TT;
    float* CST = BvT + (size_t)BB * TT;
    float* HT  = CST + (size_t)BB * TT;
    float* CMT = HT  + (size_t)BB * TT;                        // 16*128

    prefixF<<<dim3(BB), dim3(64), 0, stream>>>(d1, d2, u, F, Bvp, d2T, FT,
                                               BvT, CST, CMT, HT);
    calcM2 <<<dim3(16, TT), dim3(256), 0, stream>>>(FT, BvT, CST, CMT, HT, u, m);
    phaseC_mfma<<<dim3(BB * 8), dim3(256), 0, stream>>>(F, Bvp, d2T, m, v1, v2, out);
}

// Round 6
// 194.902 us; speedup vs baseline: 1.1749x; 1.1625x over previous
//
#include <hip/hip_runtime.h>
#include <cstdint>
#include <cstddef>

#define TT 512
#define BB 128
#define EE 128
#define SS 1024
#define NEG_INF (-1e30f)

typedef _Float16 half8 __attribute__((ext_vector_type(8)));
typedef float floatx4 __attribute__((ext_vector_type(4)));

// ---------- fp16 helpers ----------
__device__ __forceinline__ unsigned int pkh(float x, float y) {
    _Float16 hx = (_Float16)x, hy = (_Float16)y;
    unsigned short bx, by;
    __builtin_memcpy(&bx, &hx, 2); __builtin_memcpy(&by, &hy, 2);
    return (unsigned int)bx | ((unsigned int)by << 16);
}

// ============================================================
// prefixF: per-b prefix sums + range-max precompute. (original)
// ============================================================
__global__ __launch_bounds__(64) void prefixF(
    const float* __restrict__ d1, const float* __restrict__ d2,
    const float* __restrict__ u,
    float* __restrict__ F, float* __restrict__ Bv,
    float* __restrict__ d2T, float* __restrict__ FT,
    float* __restrict__ BvT, float* __restrict__ CST,
    float* __restrict__ CMT, float* __restrict__ HT)
{
    const int b = blockIdx.x;
    const int lane = threadIdx.x;
    const int t0 = lane * 8;

    float l1[8], l2[8], g[8];
#pragma unroll
    for (int j = 0; j < 8; ++j) {
        const int t = t0 + j;
        l1[j] = d1[t * BB + b];
        l2[j] = d2[t * BB + b];
        g[j] = u[t * BB + b] - l1[j] - l2[j];
    }
    float p[8], s = 0.f;
#pragma unroll
    for (int j = 0; j < 8; ++j) { s += g[j]; p[j] = s; }

    float v = s;
#pragma unroll
    for (int off = 1; off < 64; off <<= 1) {
        float o = __shfl_up(v, off);
        if (lane >= off) v += o;
    }
    const float excl = v - s;

    float Fv[8];
#pragma unroll
    for (int j = 0; j < 8; ++j) Fv[j] = excl + p[j];

#pragma unroll
    for (int j = 0; j < 8; ++j) {
        const int t = t0 + j;
        const float Fm1 = (j > 0) ? Fv[j - 1] : excl;
        const float Bvv = Fm1 - l1[j];
        F  [b * TT + t] = Fv[j];
        Bv [b * TT + t] = Bvv;
        d2T[b * TT + t] = l2[j];
        FT [t * BB + b] = Fv[j];
        BvT[t * BB + b] = Bvv;
    }

    // ---- range-max structures (chunk = 32 t = 4 lanes) ----
    float pm[8], sm[8];
    pm[0] = Fv[0];
#pragma unroll
    for (int j = 1; j < 8; ++j) pm[j] = fmaxf(pm[j - 1], Fv[j]);
    sm[7] = Fv[7];
#pragma unroll
    for (int j = 6; j >= 0; --j) sm[j] = fmaxf(sm[j + 1], Fv[j]);

    float pcar = NEG_INF, scar = NEG_INF;
#pragma unroll
    for (int off = 1; off <= 3; ++off) {
        float xu = __shfl_up(pm[7], off);
        if ((lane & 3) >= off) pcar = fmaxf(pcar, xu);
        float xd = __shfl_down(sm[0], off);
        if ((lane & 3) + off <= 3) scar = fmaxf(scar, xd);
    }

#pragma unroll
    for (int j = 0; j < 8; ++j) {
        const int t = t0 + j;
        const float Hv  = fmaxf(pcar, (j > 0) ? pm[j - 1] : NEG_INF);
        const float CSv = fmaxf(sm[j], scar);
        HT [t * BB + b] = Hv;
        CST[t * BB + b] = CSv;
    }
    if ((lane & 3) == 0)
        CMT[(lane >> 2) * BB + b] = fmaxf(sm[0], scar);
}

// ============================================================
// calcM2 (original — measured ~11 us)
// ============================================================
__global__ __launch_bounds__(256) void calcM2(
    const float* __restrict__ FT, const float* __restrict__ BvT,
    const float* __restrict__ CST, const float* __restrict__ CMT,
    const float* __restrict__ HT, const float* __restrict__ u,
    float* __restrict__ m)
{
    const int t = (int)blockIdx.y;
    const int ci = (int)blockIdx.x;
    const int ct = t >> 5;
    if (ci > ct) return;

    const int tid = threadIdx.x;
    const int b = tid & 127, h = tid >> 7;
    const int ib = 32 * ci;

    __shared__ float cand[BB][66];
    __shared__ float Tot[2][BB];
    __shared__ float red[4][64];

    const float Ft = FT[t * BB + b];

    if (ci < ct) {
        float K = HT[t * BB + b];
        for (int c = ci + 1; c < ct; ++c) K = fmaxf(K, CMT[c * BB + b]);
#pragma unroll
        for (int j = 0; j < 16; ++j) {
            const int jj = 16 * h + j;
            const int i = ib + jj;
            const float R = fmaxf(CST[i * BB + b], K);
            const float Bvv = BvT[i * BB + b];
            cand[b][2 * jj]     = Ft - fmaxf(Bvv, R);
            cand[b][2 * jj + 1] = Ft - R;
        }
    } else {
        float vv[16], sfx[16];
#pragma unroll
        for (int j = 0; j < 16; ++j) {
            const int i = ib + 16 * h + j;
            vv[j] = (i < t) ? FT[i * BB + b] : NEG_INF;
        }
        sfx[15] = vv[15];
#pragma unroll
        for (int j = 14; j >= 0; --j) sfx[j] = fmaxf(vv[j], sfx[j + 1]);
        Tot[h][b] = sfx[0];
        __syncthreads();
        const float carry = (h == 0) ? Tot[1][b] : NEG_INF;
        const float ub = u[t * BB + b];
#pragma unroll
        for (int j = 0; j < 16; ++j) {
            const int jj = 16 * h + j;
            const int i = ib + jj;
            const float R = fmaxf(sfx[j], carry);
            const float Bvv = BvT[i * BB + b];
            cand[b][2 * jj]     = Ft - fmaxf(Bvv, R);
            cand[b][2 * jj + 1] = (i == t) ? ub : (Ft - R);
        }
    }
    __syncthreads();

    {
        const int s = tid & 63, g = tid >> 6;
        float mx = NEG_INF;
        const int b0 = g * 32;
#pragma unroll 8
        for (int bb = b0; bb < b0 + 32; ++bb) mx = fmaxf(mx, cand[bb][s]);
        red[g][s] = mx;
    }
    __syncthreads();
    if (tid < 64) {
        const float r = fmaxf(fmaxf(red[0][tid], red[1][tid]),
                              fmaxf(red[2][tid], red[3][tid]));
        const int s_glob = 64 * ci + tid;
        if (s_glob < 2 * t + 2) m[(size_t)t * SS + s_glob] = r;
    }
}

// ============================================================
// phaseC_mfma: out[t,b,:] = sum_s min(a(i,t), m[t,s]) * V[b,s,:]
// Round-6:
//  - pitch RESTORED to 72 halfwords (144 B = 9x16 B -> every row
//    16 B-aligned; pitch-68 broke ds_read_b128 alignment, +23 us)
//  - keep incremental running range-max (R5: VALUBusy 25->17)
//  - pkh (RTN) restored for V-pack (absmax back to 64)
//  - NEW: 2-deep V prefetch (pvA/pvB static ping-pong, chunk loop
//    unrolled x2) -> V loads (L3-resident, ~400-700cy) get a full
//    chunk of slack instead of one MFMA cluster.  m stays 1-deep
//    (proven neutral at 2-deep in R2).
// ============================================================
#define PWH 72                 // row pitch in halfwords (16B-aligned rows)
#define PWW 36                 // row pitch in words
#define VTO 2304               // Ws = 64*36 words
#define FRO 6912               // Vt = 128*36 words
#define S0O 7488
#define BVO 8064
#define D2O 8576
#define TPO 8640
// total 8704 floats = 34816 B

#define PREFETCH_M(CK) do {                                               \
    const int i_ = 32 * (CK) + il;                                        \
    _Pragma("unroll")                                                     \
    for (int r8_ = 0; r8_ < 8; ++r8_) {                                   \
        pmv[r8_] = *(const float2*)&m[(size_t)(t0 + 8 * g + r8_) * SS + 2 * i_]; \
    } } while (0)

#define PREFETCH_V(CK, DST) do {                                          \
    const int i0_ = 32 * (CK) + 2 * vip, i1_ = i0_ + 1;                   \
    const float* p10_ = v1 + ((size_t)i0_ * BB + b) * EE;                 \
    const float* p11_ = v1 + ((size_t)i1_ * BB + b) * EE;                 \
    const float* p20_ = v2 + ((size_t)i0_ * BB + b) * EE;                 \
    const float* p21_ = v2 + ((size_t)i1_ * BB + b) * EE;                 \
    _Pragma("unroll")                                                     \
    for (int c_ = 0; c_ < 2; ++c_) {                                      \
        const int e0_ = 4 * veb + 32 * c_ + veh;                          \
        DST[4 * c_ + 0] = *(const float4*)&p10_[e0_];                     \
        DST[4 * c_ + 1] = *(const float4*)&p11_[e0_];                     \
        DST[4 * c_ + 2] = *(const float4*)&p20_[e0_];                     \
        DST[4 * c_ + 3] = *(const float4*)&p21_[e0_];                     \
    } } while (0)

#define CHUNK_BODY(CK, PV, NXV) do {                                      \
    const int ib = 32 * (CK);                                             \
    const int i = ib + il;                                                \
    const bool below = (ib < t0);          /* wave-uniform per chunk */   \
    unsigned int wreg[8];                                                 \
    {                                                                     \
        const float Ai = (i > 0) ? sh[FRO + i - 1] : 0.f;                 \
        const float Bi = sh[BVO + i];                                     \
        const int li = i - t0;                                            \
        float q, S0i = 0.f;                                               \
        if (below) {                                                      \
            S0i = sh[S0O + i];                                            \
            q = qstart;                                                   \
        } else {                                                          \
            q = NEG_INF;                                                  \
            for (int k = li; k < 8 * g; ++k)                              \
                q = fmaxf(q, sh[FRO + t0 + k]);                           \
        }                                                                 \
        _Pragma("unroll")                                                 \
        for (int r8 = 0; r8 < 8; ++r8) {                                  \
            const int t_l = 8 * g + r8;                                   \
            const float2 mv = pmv[r8];                                    \
            float w0 = 0.f, w1 = 0.f;                                     \
            if (below) {                                                  \
                const float R = fmaxf(S0i, q);                            \
                const float a0 = fmaxf(Ai, R) - fmaxf(Bi, R);             \
                const float a1 = fmaxf(Bi - R, 0.f);                      \
                w0 = fminf(a0, mv.x);                                     \
                w1 = fminf(a1, mv.y);                                     \
                q = fmaxf(q, Freg2[r8]);                                  \
            } else {                                                      \
                if (li <= t_l) {                                          \
                    const float R = q;                                    \
                    const float a0 = fmaxf(Ai, R) - fmaxf(Bi, R);         \
                    const float a1 = (li == t_l) ? sh[D2O + t_l]          \
                                                 : fmaxf(Bi - R, 0.f);    \
                    w0 = fminf(a0, mv.x);                                 \
                    w1 = fminf(a1, mv.y);                                 \
                }                                                         \
                q = fmaxf(q, (t_l >= li) ? Freg2[r8] : NEG_INF);          \
            }                                                             \
            wreg[r8] = pkh(w0, w1);                                       \
        }                                                                 \
    }                                                                     \
    uint2 vreg[8];                                                        \
    _Pragma("unroll")                                                     \
    for (int c_ = 0; c_ < 2; ++c_) {                                      \
        const float4 xa = PV[4 * c_ + 0], xb = PV[4 * c_ + 1];            \
        const float4 ya = PV[4 * c_ + 2], yb = PV[4 * c_ + 3];            \
        vreg[4 * c_ + 0] = make_uint2(pkh(xa.x, ya.x), pkh(xb.x, yb.x));  \
        vreg[4 * c_ + 1] = make_uint2(pkh(xa.y, ya.y), pkh(xb.y, yb.y));  \
        vreg[4 * c_ + 2] = make_uint2(pkh(xa.z, ya.z), pkh(xb.z, yb.z));  \
        vreg[4 * c_ + 3] = make_uint2(pkh(xa.w, ya.w), pkh(xb.w, yb.w));  \
    }                                                                     \
    __syncthreads();                 /* MFMA(prev) done reading LDS */    \
    _Pragma("unroll")                                                     \
    for (int r8 = 0; r8 < 8; ++r8)                                        \
        ((unsigned int*)sh)[(8 * g + r8) * PWW + il] = wreg[r8];          \
    {                                                                     \
        unsigned int* vt = (unsigned int*)sh + VTO;                       \
        const int dw = 2 * vip;                                           \
        _Pragma("unroll")                                                 \
        for (int c_ = 0; c_ < 2; ++c_) {                                  \
            const int e0_ = 4 * veb + 32 * c_ + veh;                      \
            *(uint2*)&vt[(e0_ + 0) * PWW + dw] = vreg[4 * c_ + 0];        \
            *(uint2*)&vt[(e0_ + 1) * PWW + dw] = vreg[4 * c_ + 1];        \
            *(uint2*)&vt[(e0_ + 2) * PWW + dw] = vreg[4 * c_ + 2];        \
            *(uint2*)&vt[(e0_ + 3) * PWW + dw] = vreg[4 * c_ + 3];        \
        }                                                                 \
    }                                                                     \
    __syncthreads();                 /* staging visible */                \
    if ((CK) + 1 < nchunks) PREFETCH_M((CK) + 1);                         \
    if ((NXV) < nchunks) PREFETCH_V((NXV), PV);                           \
    __builtin_amdgcn_s_setprio(1);                                        \
    {                                                                     \
        const _Float16* WsH = (const _Float16*)sh;                        \
        const _Float16* VtH = (const _Float16*)(sh + VTO);                \
        _Pragma("unroll")                                                 \
        for (int k2 = 0; k2 < 64; k2 += 32) {                             \
            const half8 av0 = *(const half8*)&WsH[(32 * wr + n) * PWH + kq + k2]; \
            const half8 av1 = *(const half8*)&WsH[(32 * wr + 16 + n) * PWH + kq + k2]; \
            _Pragma("unroll")                                             \
            for (int j = 0; j < 4; ++j) {                                 \
                const half8 bv = *(const half8*)&VtH[(64 * wc + 16 * j + n) * PWH + kq + k2]; \
                acc[0][j] = __builtin_amdgcn_mfma_f32_16x16x32_f16(av0, bv, acc[0][j], 0, 0, 0); \
                acc[1][j] = __builtin_amdgcn_mfma_f32_16x16x32_f16(av1, bv, acc[1][j], 0, 0, 0); \
            }                                                             \
        }                                                                 \
    }                                                                     \
    __builtin_amdgcn_s_setprio(0);                                        \
    } while (0)

__global__ __launch_bounds__(256) void phaseC_mfma(
    const float* __restrict__ F, const float* __restrict__ Bvg,
    const float* __restrict__ d2T, const float* __restrict__ m,
    const float* __restrict__ v1, const float* __restrict__ v2,
    float* __restrict__ out)
{
    const int b  = blockIdx.x & (BB - 1);
    const int k8 = blockIdx.x >> 7;
    // balanced remap: quartets {k8, k8+2, k8+4, k8+6} sum to 36 chunks.
    const int tt = 7 - (k8 ^ (((k8 + 2) >> 2) & 1));
    const int t0 = tt * 64;
    const int tid = threadIdx.x;

    __shared__ float sh[8704];

    const int lane = tid & 63, w = tid >> 6;
    const int wr = w >> 1, wc = w & 1;            // 2x2 wave grid
    const int n = lane & 15;
    const int kq = (lane >> 4) * 8;
    const int il = tid & 31, g = tid >> 5;        // W staging
    const int veb = tid & 7;                      // V staging: e quad
    const int vip = ((tid >> 3) & 7) + 8 * wc;    // i-pair 0..15
    const int veh = wr * 64;                      // e half
    const int nchunks = 2 * tt + 2;

    // ---------- pipeline registers ----------
    float4 pvA[8], pvB[8];
    float2 pmv[8];

    const int nF = t0 + 64;
    for (int k = tid; k < nF; k += 256) {
        sh[FRO + k] = F[b * TT + k];
        sh[BVO + k] = Bvg[b * TT + k];
    }
    if (tid < 64) sh[D2O + tid] = d2T[b * TT + t0 + tid];

    // issue chunk-0/1 global loads early: latency hides under prologue
    PREFETCH_V(0, pvA);
    PREFETCH_V(1, pvB);
    PREFETCH_M(0);

    __syncthreads();

    // S0[k] = max F over [k, t0-1]; TP[j] = max F over [t0, t0+j-1]
    {
        const int k1 = tid, k2 = tid + 256, k3 = tid + 512;
        sh[S0O + k1] = (k1 < t0) ? sh[FRO + k1] : NEG_INF;
        sh[S0O + k2] = (k2 < t0) ? sh[FRO + k2] : NEG_INF;
        if (k3 < 576) sh[S0O + k3] = NEG_INF;
        if (tid < 64) {
            float xi = sh[FRO + t0 + tid];
#pragma unroll
            for (int off = 1; off < 64; off <<= 1) {
                const float y = __shfl_up(xi, off);
                if (tid >= off) xi = fmaxf(xi, y);
            }
            const float ex = __shfl_up(xi, 1);
            sh[TPO + tid] = (tid == 0) ? NEG_INF : ex;
        }
        __syncthreads();
        for (int off = 1; off < t0; off <<= 1) {
            float a1 = sh[S0O + k1]; if (k1 + off < 576) a1 = fmaxf(a1, sh[S0O + k1 + off]);
            float a2 = sh[S0O + k2]; if (k2 + off < 576) a2 = fmaxf(a2, sh[S0O + k2 + off]);
            __syncthreads();
            sh[S0O + k1] = a1; sh[S0O + k2] = a2;
            __syncthreads();
        }
    }

    // per-thread constants for incremental range-max
    float Freg2[8];
#pragma unroll
    for (int j = 0; j < 8; ++j) Freg2[j] = sh[FRO + t0 + 8 * g + j];
    const float qstart = sh[TPO + 8 * g];

    floatx4 acc[2][4];
#pragma unroll
    for (int r = 0; r < 2; ++r)
#pragma unroll
        for (int j = 0; j < 4; ++j) acc[r][j] = (floatx4)0.f;

    for (int ck = 0; ck < nchunks; ck += 2) {
        CHUNK_BODY(ck,     pvA, ck + 2);
        CHUNK_BODY(ck + 1, pvB, ck + 3);
    }

    // ---- epilogue ----
    {
        const int q = lane >> 4;
#pragma unroll
        for (int r = 0; r < 2; ++r) {
#pragma unroll
            for (int j = 0; j < 4; ++j) {
#pragma unroll
                for (int reg = 0; reg < 4; ++reg) {
                    const int t = t0 + 32 * wr + 16 * r + 4 * q + reg;
                    const int col = 64 * wc + 16 * j + n;
                    out[((size_t)t * BB + b) * EE + col] = acc[r][j][reg];
                }
            }
        }
    }
}

// ============================================================
extern "C" void kernel_launch(void* const* d_in, const int* in_sizes, int n_in,
                              void* d_out, int out_size, void* d_ws, size_t ws_size,
                              hipStream_t stream) {
    const float* v1 = (const float*)d_in[0];
    const float* v2 = (const float*)d_in[1];
    const float* d1 = (const float*)d_in[2];
    const float* d2 = (const float*)d_in[3];
    const float* u  = (const float*)d_in[4];
    float* out = (float*)d_out;

    char* ws = (char*)d_ws;
    float* m   = (float*)ws;                                   // 2 MB
    float* F   = m   + (size_t)TT * SS;
    float* Bvp = F   + (size_t)BB * TT;
    float* d2T = Bvp + (size_t)BB * TT;
    float* FT  = d2T + (size_t)BB * TT;
    float* BvT = FT  + (size_t)BB * TT;
    float* CST = BvT + (size_t)BB * TT;
    float* HT  = CST + (size_t)BB * TT;
    float* CMT = HT  + (size_t)BB * TT;                        // 16*128

    prefixF<<<dim3(BB), dim3(64), 0, stream>>>(d1, d2, u, F, Bvp, d2T, FT,
                                               BvT, CST, CMT, HT);
    calcM2 <<<dim3(16, TT), dim3(256), 0, stream>>>(FT, BvT, CST, CMT, HT, u, m);
    phaseC_mfma<<<dim3(BB * 8), dim3(256), 0, stream>>>(F, Bvp, d2T, m, v1, v2, out);
}